// Round 1
// baseline (332.547 us; speedup 1.0000x reference)
//
#include <hip/hip_runtime.h>

typedef unsigned short u16;
typedef unsigned int u32;
typedef __attribute__((ext_vector_type(2))) unsigned long long u64x2;
typedef __attribute__((ext_vector_type(4))) unsigned short u16x4;
typedef __attribute__((ext_vector_type(4))) float f32x4v;
typedef __attribute__((ext_vector_type(8))) __bf16 bf16x8;
typedef __attribute__((ext_vector_type(4))) float f32x4;

#define DEV static __device__ __forceinline__

DEV u16 f2bf(float f) {
  union { float f; u32 u; } c; c.f = f;
  u32 u = c.u;
  return (u16)((u + 0x7fffu + ((u >> 16) & 1u)) >> 16);
}

// Problem constants
#define BB   2
#define LLEN 2048
#define DDIM 1024
#define HH   16
#define DH   64
#define MTOT 4096   // B*L
#define N3   3072   // 3*D

// ---------------- fp32 -> bf16 cast (x) ----------------
__global__ __launch_bounds__(256) void k_cvt(const float* __restrict__ in,
                                             u16* __restrict__ out, int n) {
  int i = (blockIdx.x * 256 + threadIdx.x) * 4;
  if (i < n) {
    f32x4v v = *reinterpret_cast<const f32x4v*>(in + i);
    u16x4 o;
    o.x = f2bf(v.x); o.y = f2bf(v.y); o.z = f2bf(v.z); o.w = f2bf(v.w);
    *reinterpret_cast<u16x4*>(out + i) = o;
  }
}

// ---------------- W [K][N] fp32 -> WT [N][K] bf16 ----------------
__global__ __launch_bounds__(256) void k_transpose_w(const float* __restrict__ W,
                                                     u16* __restrict__ WT,
                                                     int K, int N) {
  __shared__ float s[32][33];
  int k0 = blockIdx.x * 32, n0 = blockIdx.y * 32;
  int tx = threadIdx.x & 31, ty = threadIdx.x >> 5;  // ty in 0..7
#pragma unroll
  for (int i = 0; i < 4; i++)
    s[ty + i * 8][tx] = W[(k0 + ty + i * 8) * (size_t)N + n0 + tx];
  __syncthreads();
#pragma unroll
  for (int i = 0; i < 4; i++)
    WT[(size_t)(n0 + ty + i * 8) * K + k0 + tx] = f2bf(s[tx][ty + i * 8]);
}

// ---------------- phase: tanh(ps*(x @ W_phase + b_phase)) -> [b][h][l] fp32 ----------------
__global__ __launch_bounds__(256) void k_phase(const float* __restrict__ x,
                                               const float* __restrict__ Wp,
                                               const float* __restrict__ bp,
                                               const float* __restrict__ pscale,
                                               float* __restrict__ phase_t) {
  int m = blockIdx.x;                 // row in [0, B*L)
  int t = threadIdx.x;
  int h = t & 15, j = t >> 4;         // j in 0..15
  const float* xr = x + (size_t)m * DDIM;
  float acc = 0.f;
#pragma unroll 4
  for (int kk = 0; kk < 64; kk++) {
    int k = j * 64 + kk;
    acc += xr[k] * Wp[k * HH + h];
  }
  __shared__ float s[16][17];
  s[j][h] = acc;
  __syncthreads();
  if (t < 16) {
    float sum = 0.f;
#pragma unroll
    for (int jj = 0; jj < 16; jj++) sum += s[jj][t];
    float v = tanhf((*pscale) * (sum + bp[t]));
    int b = m >> 11, l = m & (LLEN - 1);
    phase_t[((size_t)(b * HH + t)) * LLEN + l] = v;
  }
}

// ---------------- 128x128 bf16 MFMA GEMM: C = A @ BT^T + bias ----------------
// A: [M][K] bf16, BT: [N][K] bf16, C: bf16 or fp32 [M][N]
template <bool BF16_OUT>
__global__ __launch_bounds__(256) void k_gemm(const u16* __restrict__ A,
                                              const u16* __restrict__ BT,
                                              const float* __restrict__ bias,
                                              void* __restrict__ C,
                                              int M, int N, int K) {
  __shared__ __attribute__((aligned(16))) u16 sA[128][40];
  __shared__ __attribute__((aligned(16))) u16 sB[128][40];
  int m0 = blockIdx.x * 128, n0 = blockIdx.y * 128;
  int t = threadIdx.x;
  int lane = t & 63, wid = t >> 6;
  int wm = wid >> 1, wn = wid & 1;    // 2x2 wave grid, 64x64 per wave
  int lc = lane & 15, lko = (lane >> 4) * 8;

  f32x4 acc[4][4] = {};

  for (int k0 = 0; k0 < K; k0 += 32) {
    __syncthreads();
#pragma unroll
    for (int i = 0; i < 2; i++) {
      int c = t + i * 256;
      int row = c >> 2, ko = (c & 3) * 8;
      *reinterpret_cast<u64x2*>(&sA[row][ko]) =
          *reinterpret_cast<const u64x2*>(&A[(size_t)(m0 + row) * K + k0 + ko]);
      *reinterpret_cast<u64x2*>(&sB[row][ko]) =
          *reinterpret_cast<const u64x2*>(&BT[(size_t)(n0 + row) * K + k0 + ko]);
    }
    __syncthreads();
    bf16x8 af[4], bfr[4];
#pragma unroll
    for (int i = 0; i < 4; i++)
      af[i] = *reinterpret_cast<const bf16x8*>(&sA[wm * 64 + i * 16 + lc][lko]);
#pragma unroll
    for (int j = 0; j < 4; j++)
      bfr[j] = *reinterpret_cast<const bf16x8*>(&sB[wn * 64 + j * 16 + lc][lko]);
#pragma unroll
    for (int i = 0; i < 4; i++)
#pragma unroll
      for (int j = 0; j < 4; j++)
        acc[i][j] = __builtin_amdgcn_mfma_f32_16x16x32_bf16(af[i], bfr[j], acc[i][j], 0, 0, 0);
  }

  int rg = lane >> 4;
#pragma unroll
  for (int i = 0; i < 4; i++) {
#pragma unroll
    for (int j = 0; j < 4; j++) {
      int col = n0 + wn * 64 + j * 16 + lc;
      float bv = bias[col];
#pragma unroll
      for (int r = 0; r < 4; r++) {
        int row = m0 + wm * 64 + i * 16 + rg * 4 + r;
        float v = acc[i][j][r] + bv;
        if (BF16_OUT)
          ((u16*)C)[(size_t)row * N + col] = f2bf(v);
        else
          ((float*)C)[(size_t)row * N + col] = v;
      }
    }
  }
}

// ---------------- V transpose: qkv v-part -> vT[b][h][dh][l] ----------------
__global__ __launch_bounds__(256) void k_vtrans(const u16* __restrict__ qkv,
                                                u16* __restrict__ vT) {
  int bh = blockIdx.y;               // b*16+h
  int lt = blockIdx.x;               // l-tile of 64
  int b = bh >> 4, h = bh & 15;
  __shared__ __attribute__((aligned(16))) u16 s[64][72];
  int t = threadIdx.x;
#pragma unroll
  for (int i = 0; i < 2; i++) {
    int c = t + i * 256;
    int l = c >> 3, ko = (c & 7) * 8;
    *reinterpret_cast<u64x2*>(&s[l][ko]) = *reinterpret_cast<const u64x2*>(
        &qkv[(size_t)(b * LLEN + lt * 64 + l) * N3 + 2 * DDIM + h * DH + ko]);
  }
  __syncthreads();
#pragma unroll
  for (int i = 0; i < 2; i++) {
    int c = t + i * 256;
    int dh = c >> 3, lo = (c & 7) * 8;
    u16 tmp[8];
#pragma unroll
    for (int j = 0; j < 8; j++) tmp[j] = s[lo + j][dh];
    *reinterpret_cast<u64x2*>(&vT[((size_t)bh * DH + dh) * LLEN + lt * 64 + lo]) =
        *reinterpret_cast<u64x2*>(tmp);
  }
}

// ---------------- flash attention with resonance term ----------------
// grid: (L/64, B*H); block 256 (4 waves x 16 query rows)
__global__ __launch_bounds__(256) void k_attn(const u16* __restrict__ qkv,
                                              const u16* __restrict__ vT,
                                              const float* __restrict__ phase_t,
                                              const int* __restrict__ mask,
                                              const float* __restrict__ rscale_p,
                                              u16* __restrict__ attn_out) {
  int bh = blockIdx.y;
  int b = bh >> 4, h = bh & 15;
  int q0 = blockIdx.x * 64;
  int t = threadIdx.x, lane = t & 63, wid = t >> 6;
  int qb = q0 + wid * 16;            // this wave's 16 query rows
  int lc = lane & 15, lg = lane >> 4;

  __shared__ __attribute__((aligned(16))) u16 kS[64][72];
  __shared__ __attribute__((aligned(16))) u16 vS[64][72];   // [dh][key]
  __shared__ __attribute__((aligned(16))) u16 pS[4][16][72];

  float rscale = *rscale_p;

  // Q fragments (A-layout: row = lc, dh = ks*32 + lg*8 + j)
  bf16x8 qf[2];
  {
    const u16* qp = &qkv[(size_t)(b * LLEN + qb + lc) * N3 + h * DH];
    qf[0] = *reinterpret_cast<const bf16x8*>(qp + lg * 8);
    qf[1] = *reinterpret_cast<const bf16x8*>(qp + 32 + lg * 8);
  }
  float pq[4];
#pragma unroll
  for (int r = 0; r < 4; r++)
    pq[r] = phase_t[(size_t)bh * LLEN + qb + lg * 4 + r];

  f32x4 o[4] = {};
  float mrow[4], lrow[4];
#pragma unroll
  for (int r = 0; r < 4; r++) { mrow[r] = -1e30f; lrow[r] = 0.f; }

  for (int kb = 0; kb < LLEN; kb += 64) {
    __syncthreads();
#pragma unroll
    for (int i = 0; i < 2; i++) {
      int c = t + i * 256;
      int row = c >> 3, ko = (c & 7) * 8;
      *reinterpret_cast<u64x2*>(&kS[row][ko]) = *reinterpret_cast<const u64x2*>(
          &qkv[(size_t)(b * LLEN + kb + row) * N3 + DDIM + h * DH + ko]);
      *reinterpret_cast<u64x2*>(&vS[row][ko]) = *reinterpret_cast<const u64x2*>(
          &vT[((size_t)bh * DH + row) * LLEN + kb + ko]);
    }
    __syncthreads();

    // S = Q K^T  (4 key blocks of 16)
    f32x4 s[4];
#pragma unroll
    for (int blk = 0; blk < 4; blk++) {
      f32x4 z = {};
      bf16x8 kf0 = *reinterpret_cast<const bf16x8*>(&kS[blk * 16 + lc][lg * 8]);
      bf16x8 kf1 = *reinterpret_cast<const bf16x8*>(&kS[blk * 16 + lc][32 + lg * 8]);
      z = __builtin_amdgcn_mfma_f32_16x16x32_bf16(qf[0], kf0, z, 0, 0, 0);
      z = __builtin_amdgcn_mfma_f32_16x16x32_bf16(qf[1], kf1, z, 0, 0, 0);
      s[blk] = z;
    }

    // scale + resonance + mask
    float pk[4]; int mk[4];
#pragma unroll
    for (int blk = 0; blk < 4; blk++) {
      int key = kb + blk * 16 + lc;
      pk[blk] = phase_t[(size_t)bh * LLEN + key];
      mk[blk] = mask[b * LLEN + key];
    }
#pragma unroll
    for (int blk = 0; blk < 4; blk++)
#pragma unroll
      for (int r = 0; r < 4; r++) {
        float d = pq[r] - pk[blk];
        float v = s[blk][r] * 0.125f - rscale * d * d;
        s[blk][r] = (mk[blk] == 0) ? -1e9f : v;
      }

    // online softmax per row (rows lg*4+r, 16 lanes per row-group hold 64 cols)
#pragma unroll
    for (int r = 0; r < 4; r++) {
      float rm = fmaxf(fmaxf(s[0][r], s[1][r]), fmaxf(s[2][r], s[3][r]));
#pragma unroll
      for (int w = 1; w < 16; w <<= 1) rm = fmaxf(rm, __shfl_xor(rm, w, 64));
      float mn = fmaxf(mrow[r], rm);
      float alpha = __expf(mrow[r] - mn);
      mrow[r] = mn;
      float rs = 0.f;
#pragma unroll
      for (int blk = 0; blk < 4; blk++) {
        float p = __expf(s[blk][r] - mn);
        s[blk][r] = p;
        rs += p;
      }
#pragma unroll
      for (int w = 1; w < 16; w <<= 1) rs += __shfl_xor(rs, w, 64);
      lrow[r] = lrow[r] * alpha + rs;
#pragma unroll
      for (int blk = 0; blk < 4; blk++) o[blk][r] *= alpha;
    }

    // P -> LDS (bf16), per-wave region
#pragma unroll
    for (int blk = 0; blk < 4; blk++)
#pragma unroll
      for (int r = 0; r < 4; r++)
        pS[wid][lg * 4 + r][blk * 16 + lc] = f2bf(s[blk][r]);
    __syncthreads();   // orders P writes before frag reads (and keeps waves together)

    // O += P V  (4 dh blocks of 16)
#pragma unroll
    for (int ks = 0; ks < 2; ks++) {
      bf16x8 pa = *reinterpret_cast<const bf16x8*>(&pS[wid][lc][ks * 32 + lg * 8]);
#pragma unroll
      for (int blk = 0; blk < 4; blk++) {
        bf16x8 vb = *reinterpret_cast<const bf16x8*>(&vS[blk * 16 + lc][ks * 32 + lg * 8]);
        o[blk] = __builtin_amdgcn_mfma_f32_16x16x32_bf16(pa, vb, o[blk], 0, 0, 0);
      }
    }
  }

  // epilogue: O / l -> attn_out bf16 [B*L][D]
#pragma unroll
  for (int blk = 0; blk < 4; blk++)
#pragma unroll
    for (int r = 0; r < 4; r++) {
      int row = b * LLEN + qb + lg * 4 + r;
      int col = h * DH + blk * 16 + lc;
      attn_out[(size_t)row * DDIM + col] = f2bf(o[blk][r] / lrow[r]);
    }
}

extern "C" void kernel_launch(void* const* d_in, const int* in_sizes, int n_in,
                              void* d_out, int out_size, void* d_ws, size_t ws_size,
                              hipStream_t stream) {
  const float* x       = (const float*)d_in[0];
  const int*   mask    = (const int*)d_in[1];
  const float* W_qkv   = (const float*)d_in[2];
  const float* b_qkv   = (const float*)d_in[3];
  const float* W_out   = (const float*)d_in[4];
  const float* b_out   = (const float*)d_in[5];
  const float* W_phase = (const float*)d_in[6];
  const float* b_phase = (const float*)d_in[7];
  const float* rscale  = (const float*)d_in[8];
  const float* pscale  = (const float*)d_in[9];
  float* out = (float*)d_out;

  char* ws = (char*)d_ws;
  u16* x_bf     = (u16*)(ws + 0);           //  8.0 MB
  u16* wt_qkv   = (u16*)(ws + 8388608);     //  6.0 MB
  u16* wt_out   = (u16*)(ws + 14680064);    //  2.0 MB
  u16* qkv      = (u16*)(ws + 16777216);    // 24.0 MB
  u16* vT       = (u16*)(ws + 41943040);    //  8.0 MB
  u16* attn_out = (u16*)(ws + 50331648);    //  8.0 MB
  float* phase_t = (float*)(ws + 58720256); //  0.25 MB  (total ~56.3 MB)

  // 1. x -> bf16
  k_cvt<<<MTOT * DDIM / 4 / 256, 256, 0, stream>>>(x, x_bf, MTOT * DDIM);
  // 2. weight transposes
  k_transpose_w<<<dim3(DDIM / 32, N3 / 32), 256, 0, stream>>>(W_qkv, wt_qkv, DDIM, N3);
  k_transpose_w<<<dim3(DDIM / 32, DDIM / 32), 256, 0, stream>>>(W_out, wt_out, DDIM, DDIM);
  // 3. phase (fp32)
  k_phase<<<MTOT, 256, 0, stream>>>(x, W_phase, b_phase, pscale, phase_t);
  // 4. QKV GEMM -> bf16
  k_gemm<true><<<dim3(MTOT / 128, N3 / 128), 256, 0, stream>>>(
      x_bf, wt_qkv, b_qkv, qkv, MTOT, N3, DDIM);
  // 5. V transpose
  k_vtrans<<<dim3(LLEN / 64, BB * HH), 256, 0, stream>>>(qkv, vT);
  // 6. flash attention with resonance
  k_attn<<<dim3(LLEN / 64, BB * HH), 256, 0, stream>>>(
      qkv, vT, phase_t, mask, rscale, attn_out);
  // 7. output GEMM -> fp32
  k_gemm<false><<<dim3(MTOT / 128, DDIM / 128), 256, 0, stream>>>(
      attn_out, wt_out, b_out, out, MTOT, DDIM, DDIM);
}

// Round 3
// 305.168 us; speedup vs baseline: 1.0897x; 1.0897x over previous
//
#include <hip/hip_runtime.h>

typedef unsigned short u16;
typedef unsigned int u32;
typedef __attribute__((ext_vector_type(2))) unsigned long long u64x2;
typedef __attribute__((ext_vector_type(4))) unsigned short u16x4;
typedef __attribute__((ext_vector_type(8))) __bf16 bf16x8;
typedef __attribute__((ext_vector_type(4))) float f32x4;
typedef __attribute__((ext_vector_type(2))) float f32x2;

#define DEV static __device__ __forceinline__
#define LOG2E 1.4426950408889634f

DEV u16 f2bf(float f) { __bf16 h = (__bf16)f; return __builtin_bit_cast(u16, h); }

// Problem constants
#define BB   2
#define LLEN 2048
#define DDIM 1024
#define HH   16
#define DH   64
#define MTOT 4096   // B*L
#define N3   3072   // 3*D

// ---------------- async global->LDS, 16B per lane ----------------
DEV void gl16(const void* g, void* l) {
  __builtin_amdgcn_global_load_lds(
      (const __attribute__((address_space(1))) void*)g,
      (__attribute__((address_space(3))) void*)l, 16, 0, 0);
}

// Stage a 64-row x 128B tile (row stride gsb bytes) into linear LDS with
// XOR swizzle: LDS[row*128 + cb] = G[row][cb ^ ((row&7)<<4)].
// 8 insts of 1KB; 4 waves x 2 insts.
DEV void stage64(const u16* org, size_t gsb, u16* lds, int lane, int wid) {
#pragma unroll
  for (int j = 0; j < 2; j++) {
    int inst = wid * 2 + j;
    int r8 = lane >> 3;                       // row within inst, == row&7
    const char* src = (const char*)org + (size_t)(inst * 8 + r8) * gsb +
                      (((lane & 7) ^ r8) << 4);
    gl16(src, (char*)lds + inst * 1024);
  }
}
DEV bf16x8 read128(const u16* tile, int row, int colb) {
  return *reinterpret_cast<const bf16x8*>(
      (const char*)tile + row * 128 + (colb ^ ((row & 7) << 4)));
}

// Stage a 128-row x 64B tile: LDS[row*64 + cb] = G[row][cb ^ ((row&3)<<4)].
// 8 insts of 1KB (16 rows each); 4 waves x 2 insts.
DEV void stage128x32(const u16* org, size_t gsb, u16* lds, int lane, int wid) {
#pragma unroll
  for (int j = 0; j < 2; j++) {
    int inst = wid + j * 4;
    int r16 = lane >> 2;
    const char* src = (const char*)org + (size_t)(inst * 16 + r16) * gsb +
                      ((((lane & 3) ^ (r16 & 3))) << 4);
    gl16(src, (char*)lds + inst * 1024);
  }
}
DEV bf16x8 read64(const u16* tile, int row, int colb) {
  return *reinterpret_cast<const bf16x8*>(
      (const char*)tile + row * 64 + (colb ^ ((row & 3) << 4)));
}

// ---------------- fp32 -> bf16 cast (x) ----------------
__global__ __launch_bounds__(256) void k_cvt(const float* __restrict__ in,
                                             u16* __restrict__ out, int n) {
  int i = (blockIdx.x * 256 + threadIdx.x) * 4;
  if (i < n) {
    f32x4 v = *reinterpret_cast<const f32x4*>(in + i);
    u16x4 o;
    o.x = f2bf(v.x); o.y = f2bf(v.y); o.z = f2bf(v.z); o.w = f2bf(v.w);
    *reinterpret_cast<u16x4*>(out + i) = o;
  }
}

// ---------------- W [K][N] fp32 -> WT [N][K] bf16 ----------------
__global__ __launch_bounds__(256) void k_transpose_w(const float* __restrict__ W,
                                                     u16* __restrict__ WT,
                                                     int K, int N) {
  __shared__ float s[32][33];
  int k0 = blockIdx.x * 32, n0 = blockIdx.y * 32;
  int tx = threadIdx.x & 31, ty = threadIdx.x >> 5;
#pragma unroll
  for (int i = 0; i < 4; i++)
    s[ty + i * 8][tx] = W[(k0 + ty + i * 8) * (size_t)N + n0 + tx];
  __syncthreads();
#pragma unroll
  for (int i = 0; i < 4; i++)
    WT[(size_t)(n0 + ty + i * 8) * K + k0 + tx] = f2bf(s[tx][ty + i * 8]);
}

// ---------------- phase: ppk[bh][l] = {pk, -rs*log2e*pk^2 (or -1e9 if masked)} ----------------
__global__ __launch_bounds__(256) void k_phase(const float* __restrict__ x,
                                               const float* __restrict__ Wp,
                                               const float* __restrict__ bp,
                                               const float* __restrict__ pscale,
                                               const float* __restrict__ rscale,
                                               const int* __restrict__ mask,
                                               f32x2* __restrict__ ppk) {
  int m = blockIdx.x;
  int t = threadIdx.x;
  int h = t & 15, j = t >> 4;
  const float* xr = x + (size_t)m * DDIM;
  float acc = 0.f;
#pragma unroll 4
  for (int kk = 0; kk < 64; kk++) {
    int k = j * 64 + kk;
    acc += xr[k] * Wp[k * HH + h];
  }
  __shared__ float s[16][17];
  s[j][h] = acc;
  __syncthreads();
  if (t < 16) {
    float sum = 0.f;
#pragma unroll
    for (int jj = 0; jj < 16; jj++) sum += s[jj][t];
    float v = tanhf((*pscale) * (sum + bp[t]));
    int b = m >> 11, l = m & (LLEN - 1);
    float kb = (mask[m] == 0) ? -1.0e9f : (-(*rscale) * LOG2E) * v * v;
    f32x2 o; o.x = v; o.y = kb;
    ppk[((size_t)(b * HH + t)) * LLEN + l] = o;
  }
}

// ---------------- 128x128 bf16 MFMA GEMM (m97-style, dbuf + global_load_lds) ----------------
template <bool BF16_OUT>
__global__ __launch_bounds__(256) void k_gemm(const u16* __restrict__ A,
                                              const u16* __restrict__ BT,
                                              const float* __restrict__ bias,
                                              void* __restrict__ C,
                                              int M, int N, int K) {
  __shared__ __attribute__((aligned(16))) u16 sA[2][128 * 32];
  __shared__ __attribute__((aligned(16))) u16 sB[2][128 * 32];
  int m0 = blockIdx.x * 128, n0 = blockIdx.y * 128;
  int t = threadIdx.x, lane = t & 63, wid = t >> 6;
  int wm = wid >> 1, wn = wid & 1;
  int lc = lane & 15, lg = lane >> 4;

  const u16* Ao = A + (size_t)m0 * K;
  const u16* Bo = BT + (size_t)n0 * K;

  f32x4 acc[4][4] = {};
  stage128x32(Ao, (size_t)K * 2, sA[0], lane, wid);
  stage128x32(Bo, (size_t)K * 2, sB[0], lane, wid);
  __syncthreads();
  int cur = 0;
  int NT = K >> 5;
  for (int kt = 0; kt < NT; kt++) {
    if (kt + 1 < NT) {
      stage128x32(Ao + (kt + 1) * 32, (size_t)K * 2, sA[cur ^ 1], lane, wid);
      stage128x32(Bo + (kt + 1) * 32, (size_t)K * 2, sB[cur ^ 1], lane, wid);
    }
    bf16x8 af[4], bfr[4];
#pragma unroll
    for (int i = 0; i < 4; i++) af[i] = read64(sA[cur], wm * 64 + i * 16 + lc, lg * 16);
#pragma unroll
    for (int j = 0; j < 4; j++) bfr[j] = read64(sB[cur], wn * 64 + j * 16 + lc, lg * 16);
#pragma unroll
    for (int i = 0; i < 4; i++)
#pragma unroll
      for (int j = 0; j < 4; j++)
        acc[i][j] = __builtin_amdgcn_mfma_f32_16x16x32_bf16(af[i], bfr[j], acc[i][j], 0, 0, 0);
    __syncthreads();
    cur ^= 1;
  }

  int rg = lane >> 4;
#pragma unroll
  for (int i = 0; i < 4; i++) {
#pragma unroll
    for (int j = 0; j < 4; j++) {
      int col = n0 + wn * 64 + j * 16 + lc;
      float bv = bias[col];
#pragma unroll
      for (int r = 0; r < 4; r++) {
        int row = m0 + wm * 64 + i * 16 + rg * 4 + r;
        float v = acc[i][j][r] + bv;
        if (BF16_OUT)
          ((u16*)C)[(size_t)row * N + col] = f2bf(v);
        else
          ((float*)C)[(size_t)row * N + col] = v;
      }
    }
  }
}

// ---------------- V transpose: qkv v-part -> vT[b][h][dh][l] ----------------
__global__ __launch_bounds__(256) void k_vtrans(const u16* __restrict__ qkv,
                                                u16* __restrict__ vT) {
  int bh = blockIdx.y;
  int lt = blockIdx.x;
  int b = bh >> 4, h = bh & 15;
  __shared__ __attribute__((aligned(16))) u16 s[64][72];
  int t = threadIdx.x;
#pragma unroll
  for (int i = 0; i < 2; i++) {
    int c = t + i * 256;
    int l = c >> 3, ko = (c & 7) * 8;
    *reinterpret_cast<u64x2*>(&s[l][ko]) = *reinterpret_cast<const u64x2*>(
        &qkv[(size_t)(b * LLEN + lt * 64 + l) * N3 + 2 * DDIM + h * DH + ko]);
  }
  __syncthreads();
#pragma unroll
  for (int i = 0; i < 2; i++) {
    int c = t + i * 256;
    int dh = c >> 3, lo = (c & 7) * 8;
    u16 tmp[8];
#pragma unroll
    for (int j = 0; j < 8; j++) tmp[j] = s[lo + j][dh];
    *reinterpret_cast<u64x2*>(&vT[((size_t)bh * DH + dh) * LLEN + lt * 64 + lo]) =
        *reinterpret_cast<u64x2*>(tmp);
  }
}

// ---------------- flash attention with resonance term ----------------
// grid: (L/64, B*H); block 256 (4 waves x 16 query rows)
__global__ __launch_bounds__(256) void k_attn(const u16* __restrict__ qkv,
                                              const u16* __restrict__ vT,
                                              const f32x2* __restrict__ ppk,
                                              const float* __restrict__ rscale_p,
                                              u16* __restrict__ attn_out) {
  __shared__ __attribute__((aligned(16))) u16 kS[2][64 * 64];
  __shared__ __attribute__((aligned(16))) u16 vS[2][64 * 64];
  __shared__ __attribute__((aligned(16))) float pS[4][16][68];

  int bh = blockIdx.y, b = bh >> 4, h = bh & 15;
  int q0 = blockIdx.x * 64;
  int t = threadIdx.x, lane = t & 63, wid = t >> 6;
  int qb = q0 + wid * 16;
  int lc = lane & 15, lg = lane >> 4;

  const float rs2 = (*rscale_p) * LOG2E;
  const float c1 = 0.125f * LOG2E;

  const f32x2* pprow = ppk + (size_t)bh * LLEN;

  // Q fragments (A-layout: row=lc, k=lg*8+j)
  bf16x8 qf0, qf1;
  {
    const u16* qp = &qkv[(size_t)(b * LLEN + qb + lc) * N3 + h * DH + lg * 8];
    qf0 = *reinterpret_cast<const bf16x8*>(qp);
    qf1 = *reinterpret_cast<const bf16x8*>(qp + 32);
  }
  float wq[4];
#pragma unroll
  for (int r = 0; r < 4; r++)
    wq[r] = 2.f * rs2 * pprow[qb + lg * 4 + r].x;

  const u16* kg = qkv + (size_t)(b * LLEN) * N3 + DDIM + h * DH;  // rows: key
  const u16* vg = vT + (size_t)bh * DH * LLEN;                    // rows: dh

  // prologue: stage tile 0, load phase pairs for tile 0
  stage64(kg, (size_t)N3 * 2, kS[0], lane, wid);
  stage64(vg, (size_t)LLEN * 2, vS[0], lane, wid);
  f32x2 pcur[4], pnext[4];
#pragma unroll
  for (int blk = 0; blk < 4; blk++) pcur[blk] = pprow[blk * 16 + lc];

  f32x4 o[4] = {};
  float mrow[4], lrow[4];
#pragma unroll
  for (int r = 0; r < 4; r++) { mrow[r] = -1e30f; lrow[r] = 0.f; }

  __syncthreads();
  int cur = 0;
  for (int kt = 0; kt < LLEN / 64; kt++) {
    int kb = kt * 64;
    // issue next tile's loads (overlap with compute below)
    if (kt + 1 < LLEN / 64) {
      stage64(kg + (size_t)(kb + 64) * N3, (size_t)N3 * 2, kS[cur ^ 1], lane, wid);
      stage64(vg + kb + 64, (size_t)LLEN * 2, vS[cur ^ 1], lane, wid);
#pragma unroll
      for (int blk = 0; blk < 4; blk++) pnext[blk] = pprow[kb + 64 + blk * 16 + lc];
    }

    // S = Q K^T
    f32x4 sv[4];
#pragma unroll
    for (int blk = 0; blk < 4; blk++) {
      f32x4 z = {};
      bf16x8 kf0 = read128(kS[cur], blk * 16 + lc, lg * 16);
      bf16x8 kf1 = read128(kS[cur], blk * 16 + lc, 64 + lg * 16);
      z = __builtin_amdgcn_mfma_f32_16x16x32_bf16(qf0, kf0, z, 0, 0, 0);
      z = __builtin_amdgcn_mfma_f32_16x16x32_bf16(qf1, kf1, z, 0, 0, 0);
      sv[blk] = z;
    }

    // logits (log2-space): l2 = s*c1 + wq*pk + kbias   (2 fma/elem)
#pragma unroll
    for (int blk = 0; blk < 4; blk++) {
      float pk = pcur[blk].x, kbias = pcur[blk].y;
#pragma unroll
      for (int r = 0; r < 4; r++)
        sv[blk][r] = fmaf(sv[blk][r], c1, fmaf(wq[r], pk, kbias));
    }

    // online softmax per row (16 lanes per row-group hold the 64 keys)
#pragma unroll
    for (int r = 0; r < 4; r++) {
      float rm = fmaxf(fmaxf(sv[0][r], sv[1][r]), fmaxf(sv[2][r], sv[3][r]));
#pragma unroll
      for (int w = 1; w < 16; w <<= 1) rm = fmaxf(rm, __shfl_xor(rm, w, 64));
      float mn = fmaxf(mrow[r], rm);
      float alpha = __builtin_amdgcn_exp2f(mrow[r] - mn);
      mrow[r] = mn;
      float ssum = 0.f;
#pragma unroll
      for (int blk = 0; blk < 4; blk++) {
        float p = __builtin_amdgcn_exp2f(sv[blk][r] - mn);
        sv[blk][r] = p;
        ssum += p;
      }
#pragma unroll
      for (int w = 1; w < 16; w <<= 1) ssum += __shfl_xor(ssum, w, 64);
      lrow[r] = lrow[r] * alpha + ssum;
#pragma unroll
      for (int blk = 0; blk < 4; blk++) o[blk][r] *= alpha;
    }

    // P (f32) -> per-wave LDS; no barrier needed (wave-private region)
#pragma unroll
    for (int r = 0; r < 4; r++)
#pragma unroll
      for (int blk = 0; blk < 4; blk++)
        pS[wid][lg * 4 + r][blk * 16 + lc] = sv[blk][r];

    // O += P V (read P transposed, convert pairs via v_cvt_pk_bf16_f32)
#pragma unroll
    for (int ks = 0; ks < 2; ks++) {
      const float* pp_ = &pS[wid][lc][ks * 32 + lg * 8];
      f32x4 a0 = *reinterpret_cast<const f32x4*>(pp_);
      f32x4 a1 = *reinterpret_cast<const f32x4*>(pp_ + 4);
      bf16x8 pa;
#pragma unroll
      for (int j = 0; j < 4; j++) pa[j] = (__bf16)a0[j];
#pragma unroll
      for (int j = 0; j < 4; j++) pa[4 + j] = (__bf16)a1[j];
#pragma unroll
      for (int blk = 0; blk < 4; blk++) {
        bf16x8 vb = read128(vS[cur], blk * 16 + lc, ks * 64 + lg * 16);
        o[blk] = __builtin_amdgcn_mfma_f32_16x16x32_bf16(pa, vb, o[blk], 0, 0, 0);
      }
    }

#pragma unroll
    for (int blk = 0; blk < 4; blk++) pcur[blk] = pnext[blk];
    __syncthreads();  // drains staged loads; protects buffer reuse
    cur ^= 1;
  }

  // epilogue
#pragma unroll
  for (int r = 0; r < 4; r++) {
    float inv = 1.0f / lrow[r];
    int row = b * LLEN + qb + lg * 4 + r;
#pragma unroll
    for (int blk = 0; blk < 4; blk++) {
      int col = h * DH + blk * 16 + lc;
      attn_out[(size_t)row * DDIM + col] = f2bf(o[blk][r] * inv);
    }
  }
}

extern "C" void kernel_launch(void* const* d_in, const int* in_sizes, int n_in,
                              void* d_out, int out_size, void* d_ws, size_t ws_size,
                              hipStream_t stream) {
  const float* x       = (const float*)d_in[0];
  const int*   mask    = (const int*)d_in[1];
  const float* W_qkv   = (const float*)d_in[2];
  const float* b_qkv   = (const float*)d_in[3];
  const float* W_out   = (const float*)d_in[4];
  const float* b_out   = (const float*)d_in[5];
  const float* W_phase = (const float*)d_in[6];
  const float* b_phase = (const float*)d_in[7];
  const float* rscale  = (const float*)d_in[8];
  const float* pscale  = (const float*)d_in[9];
  float* out = (float*)d_out;

  char* ws = (char*)d_ws;
  u16* x_bf     = (u16*)(ws + 0);           //  8.0 MB
  u16* wt_qkv   = (u16*)(ws + 8388608);     //  6.0 MB
  u16* wt_out   = (u16*)(ws + 14680064);    //  2.0 MB
  u16* qkv      = (u16*)(ws + 16777216);    // 24.0 MB
  u16* vT       = (u16*)(ws + 41943040);    //  8.0 MB
  u16* attn_out = (u16*)(ws + 50331648);    //  8.0 MB
  f32x2* ppk    = (f32x2*)(ws + 58720256);  //  0.5 MB

  k_cvt<<<MTOT * DDIM / 4 / 256, 256, 0, stream>>>(x, x_bf, MTOT * DDIM);
  k_transpose_w<<<dim3(DDIM / 32, N3 / 32), 256, 0, stream>>>(W_qkv, wt_qkv, DDIM, N3);
  k_transpose_w<<<dim3(DDIM / 32, DDIM / 32), 256, 0, stream>>>(W_out, wt_out, DDIM, DDIM);
  k_phase<<<MTOT, 256, 0, stream>>>(x, W_phase, b_phase, pscale, rscale, mask, ppk);
  k_gemm<true><<<dim3(MTOT / 128, N3 / 128), 256, 0, stream>>>(
      x_bf, wt_qkv, b_qkv, qkv, MTOT, N3, DDIM);
  k_vtrans<<<dim3(LLEN / 64, BB * HH), 256, 0, stream>>>(qkv, vT);
  k_attn<<<dim3(LLEN / 64, BB * HH), 256, 0, stream>>>(
      qkv, vT, ppk, rscale, attn_out);
  k_gemm<false><<<dim3(MTOT / 128, DDIM / 128), 256, 0, stream>>>(
      attn_out, wt_out, b_out, out, MTOT, DDIM, DDIM);
}

// Round 4
// 250.327 us; speedup vs baseline: 1.3285x; 1.2191x over previous
//
#include <hip/hip_runtime.h>

typedef unsigned short u16;
typedef unsigned int u32;
typedef __attribute__((ext_vector_type(2))) unsigned long long u64x2;
typedef __attribute__((ext_vector_type(4))) unsigned short u16x4;
typedef __attribute__((ext_vector_type(8))) __bf16 bf16x8;
typedef __attribute__((ext_vector_type(4))) float f32x4;
typedef __attribute__((ext_vector_type(2))) float f32x2;

#define DEV static __device__ __forceinline__
#define LOG2E 1.4426950408889634f

DEV u16 f2bf(float f) { __bf16 h = (__bf16)f; return __builtin_bit_cast(u16, h); }

// Problem constants
#define BB   2
#define LLEN 2048
#define DDIM 1024
#define HH   16
#define DH   64
#define MTOT 4096   // B*L
#define N3   3072   // 3*D

// ---------------- async global->LDS, 16B per lane ----------------
DEV void gl16(const void* g, void* l) {
  __builtin_amdgcn_global_load_lds(
      (const __attribute__((address_space(1))) void*)g,
      (__attribute__((address_space(3))) void*)l, 16, 0, 0);
}

// Stage a 64-row x 128B tile into linear LDS with XOR swizzle on row bits
// {0,1,3}: LDS[row*128 + cb] = G[row][cb ^ (swz3(row)<<4)],
// swz3(row) = (row&3) | (((row>>3)&1)<<2).
// (K-tile QK^T A-rows vary in row bits {0,1,3,4}; V-rows in {0..3} — both map
// to 8 distinct 16B slots per 16 lanes => 2-way = free.)
DEV void stage64(const u16* org, size_t gsb, u16* lds, int lane, int wid) {
#pragma unroll
  for (int j = 0; j < 2; j++) {
    int inst = wid * 2 + j;
    int r8 = lane >> 3;                      // row&7
    int row = inst * 8 + r8;
    int s = (r8 & 3) | ((inst & 1) << 2);    // == swz3(row)
    const char* src = (const char*)org + (size_t)row * gsb +
                      (((lane & 7) ^ s) << 4);
    gl16(src, (char*)lds + inst * 1024);
  }
}
DEV bf16x8 read128s(const u16* tile, int row, int colb) {
  return *reinterpret_cast<const bf16x8*>(
      (const char*)tile + row * 128 +
      (colb ^ (((row & 3) | (((row >> 3) & 1) << 2)) << 4)));
}

// Stage a 128-row x 64B tile: LDS[row*64 + cb] = G[row][cb ^ ((row&3)<<4)].
DEV void stage128x32(const u16* org, size_t gsb, u16* lds, int lane, int wid) {
#pragma unroll
  for (int j = 0; j < 2; j++) {
    int inst = wid + j * 4;
    int r16 = lane >> 2;
    const char* src = (const char*)org + (size_t)(inst * 16 + r16) * gsb +
                      ((((lane & 3) ^ (r16 & 3))) << 4);
    gl16(src, (char*)lds + inst * 1024);
  }
}
DEV bf16x8 read64(const u16* tile, int row, int colb) {
  return *reinterpret_cast<const bf16x8*>(
      (const char*)tile + row * 64 + (colb ^ ((row & 3) << 4)));
}

// ---------------- fp32 -> bf16 cast (x) ----------------
__global__ __launch_bounds__(256) void k_cvt(const float* __restrict__ in,
                                             u16* __restrict__ out, int n) {
  int i = (blockIdx.x * 256 + threadIdx.x) * 4;
  if (i < n) {
    f32x4 v = *reinterpret_cast<const f32x4*>(in + i);
    u16x4 o;
    o.x = f2bf(v.x); o.y = f2bf(v.y); o.z = f2bf(v.z); o.w = f2bf(v.w);
    *reinterpret_cast<u16x4*>(out + i) = o;
  }
}

// ---------------- W [K][N] fp32 -> WT [N][K] bf16 ----------------
__global__ __launch_bounds__(256) void k_transpose_w(const float* __restrict__ W,
                                                     u16* __restrict__ WT,
                                                     int K, int N) {
  __shared__ float s[32][33];
  int k0 = blockIdx.x * 32, n0 = blockIdx.y * 32;
  int tx = threadIdx.x & 31, ty = threadIdx.x >> 5;
#pragma unroll
  for (int i = 0; i < 4; i++)
    s[ty + i * 8][tx] = W[(k0 + ty + i * 8) * (size_t)N + n0 + tx];
  __syncthreads();
#pragma unroll
  for (int i = 0; i < 4; i++)
    WT[(size_t)(n0 + ty + i * 8) * K + k0 + tx] = f2bf(s[tx][ty + i * 8]);
}

// ---------------- phase: ppk[bh][l] = {pk, -rs*log2e*pk^2 (or -1e9 if masked)} ----------------
__global__ __launch_bounds__(256) void k_phase(const float* __restrict__ x,
                                               const float* __restrict__ Wp,
                                               const float* __restrict__ bp,
                                               const float* __restrict__ pscale,
                                               const float* __restrict__ rscale,
                                               const int* __restrict__ mask,
                                               f32x2* __restrict__ ppk) {
  int m = blockIdx.x;
  int t = threadIdx.x;
  int h = t & 15, j = t >> 4;
  const float* xr = x + (size_t)m * DDIM;
  float acc = 0.f;
#pragma unroll 4
  for (int kk = 0; kk < 64; kk++) {
    int k = j * 64 + kk;
    acc += xr[k] * Wp[k * HH + h];
  }
  __shared__ float s[16][17];
  s[j][h] = acc;
  __syncthreads();
  if (t < 16) {
    float sum = 0.f;
#pragma unroll
    for (int jj = 0; jj < 16; jj++) sum += s[jj][t];
    float v = tanhf((*pscale) * (sum + bp[t]));
    int b = m >> 11, l = m & (LLEN - 1);
    float kb = (mask[m] == 0) ? -1.0e9f : (-(*rscale) * LOG2E) * v * v;
    f32x2 o; o.x = v; o.y = kb;
    ppk[((size_t)(b * HH + t)) * LLEN + l] = o;
  }
}

// ---------------- 128x128 bf16 MFMA GEMM (dbuf + global_load_lds) ----------------
template <bool BF16_OUT>
__global__ __launch_bounds__(256) void k_gemm(const u16* __restrict__ A,
                                              const u16* __restrict__ BT,
                                              const float* __restrict__ bias,
                                              void* __restrict__ C,
                                              int M, int N, int K) {
  __shared__ __attribute__((aligned(16))) u16 sA[2][128 * 32];
  __shared__ __attribute__((aligned(16))) u16 sB[2][128 * 32];
  int m0 = blockIdx.x * 128, n0 = blockIdx.y * 128;
  int t = threadIdx.x, lane = t & 63, wid = t >> 6;
  int wm = wid >> 1, wn = wid & 1;
  int lc = lane & 15, lg = lane >> 4;

  const u16* Ao = A + (size_t)m0 * K;
  const u16* Bo = BT + (size_t)n0 * K;

  f32x4 acc[4][4] = {};
  stage128x32(Ao, (size_t)K * 2, sA[0], lane, wid);
  stage128x32(Bo, (size_t)K * 2, sB[0], lane, wid);
  __syncthreads();
  int cur = 0;
  int NT = K >> 5;
  for (int kt = 0; kt < NT; kt++) {
    if (kt + 1 < NT) {
      stage128x32(Ao + (kt + 1) * 32, (size_t)K * 2, sA[cur ^ 1], lane, wid);
      stage128x32(Bo + (kt + 1) * 32, (size_t)K * 2, sB[cur ^ 1], lane, wid);
    }
    bf16x8 af[4], bfr[4];
#pragma unroll
    for (int i = 0; i < 4; i++) af[i] = read64(sA[cur], wm * 64 + i * 16 + lc, lg * 16);
#pragma unroll
    for (int j = 0; j < 4; j++) bfr[j] = read64(sB[cur], wn * 64 + j * 16 + lc, lg * 16);
    __builtin_amdgcn_s_setprio(1);
#pragma unroll
    for (int i = 0; i < 4; i++)
#pragma unroll
      for (int j = 0; j < 4; j++)
        acc[i][j] = __builtin_amdgcn_mfma_f32_16x16x32_bf16(af[i], bfr[j], acc[i][j], 0, 0, 0);
    __builtin_amdgcn_s_setprio(0);
    __syncthreads();
    cur ^= 1;
  }

  int rg = lane >> 4;
#pragma unroll
  for (int i = 0; i < 4; i++) {
#pragma unroll
    for (int j = 0; j < 4; j++) {
      int col = n0 + wn * 64 + j * 16 + lc;
      float bv = bias[col];
#pragma unroll
      for (int r = 0; r < 4; r++) {
        int row = m0 + wm * 64 + i * 16 + rg * 4 + r;
        float v = acc[i][j][r] + bv;
        if (BF16_OUT)
          ((u16*)C)[(size_t)row * N + col] = f2bf(v);
        else
          ((float*)C)[(size_t)row * N + col] = v;
      }
    }
  }
}

// ---------------- V transpose: qkv v-part -> vT[b][h][dh][l] ----------------
__global__ __launch_bounds__(256) void k_vtrans(const u16* __restrict__ qkv,
                                                u16* __restrict__ vT) {
  int bh = blockIdx.y;
  int lt = blockIdx.x;
  int b = bh >> 4, h = bh & 15;
  __shared__ __attribute__((aligned(16))) u16 s[64][72];
  int t = threadIdx.x;
#pragma unroll
  for (int i = 0; i < 2; i++) {
    int c = t + i * 256;
    int l = c >> 3, ko = (c & 7) * 8;
    *reinterpret_cast<u64x2*>(&s[l][ko]) = *reinterpret_cast<const u64x2*>(
        &qkv[(size_t)(b * LLEN + lt * 64 + l) * N3 + 2 * DDIM + h * DH + ko]);
  }
  __syncthreads();
#pragma unroll
  for (int i = 0; i < 2; i++) {
    int c = t + i * 256;
    int dh = c >> 3, lo = (c & 7) * 8;
    u16 tmp[8];
#pragma unroll
    for (int j = 0; j < 8; j++) tmp[j] = s[lo + j][dh];
    *reinterpret_cast<u64x2*>(&vT[((size_t)bh * DH + dh) * LLEN + lt * 64 + lo]) =
        *reinterpret_cast<u64x2*>(tmp);
  }
}

// ---------------- flash attention, swapped QK^T, softmax in-lane ----------------
// Key permutation: QK^T mfma #blk uses K rows f(blk,m)=32*(blk>>1)+8*(m>>2)+
// 4*(blk&1)+(m&3). Then lane (lc,lg) owns S[q=qb+lc][key=32ks+8lg+4h+r] in
// sv[2ks+h][r], which is EXACTLY PV A-frag element e=4h+r of frag ks —
// P->PV needs only in-lane bf16 casts. V needs no permutation (physical key
// == logical k index: 32ks+lg*8+j). Softmax: per-lane q, in-lane reduce over
// 16 + 2 shfl_xor over lg groups.
__global__ __launch_bounds__(256, 4) void k_attn(const u16* __restrict__ qkv,
                                                 const u16* __restrict__ vT,
                                                 const f32x2* __restrict__ ppk,
                                                 const float* __restrict__ rscale_p,
                                                 u16* __restrict__ attn_out) {
  __shared__ __attribute__((aligned(16))) u16 kS[2][64 * 64];
  __shared__ __attribute__((aligned(16))) u16 vS[2][64 * 64];

  int bh = blockIdx.y, b = bh >> 4, h = bh & 15;
  int q0 = blockIdx.x * 64;
  int t = threadIdx.x, lane = t & 63, wid = t >> 6;
  int qb = q0 + wid * 16;
  int lc = lane & 15, lg = lane >> 4;

  const float rs2 = (*rscale_p) * LOG2E;
  const float c1 = 0.125f * LOG2E;
  const f32x2* pprow = ppk + (size_t)bh * LLEN;

  // Q B-fragment: lane holds Q[qb+lc][dh=lg*8+j]
  bf16x8 qf0, qf1;
  {
    const u16* qp = &qkv[(size_t)(b * LLEN + qb + lc) * N3 + h * DH + lg * 8];
    qf0 = *reinterpret_cast<const bf16x8*>(qp);
    qf1 = *reinterpret_cast<const bf16x8*>(qp + 32);
  }
  float wq = 2.f * rs2 * pprow[qb + lc].x;   // per-lane scalar (q = lc)

  const u16* kg = qkv + (size_t)(b * LLEN) * N3 + DDIM + h * DH;  // rows: key
  const u16* vg = vT + (size_t)bh * DH * LLEN;                    // rows: dh

  stage64(kg, (size_t)N3 * 2, kS[0], lane, wid);
  stage64(vg, (size_t)LLEN * 2, vS[0], lane, wid);

  f32x4 o[4] = {};
  float mrow = -1e30f, lrow = 0.f;
  int arow = ((lc >> 2) << 3) | (lc & 3);    // f(blk,lc) base

  __syncthreads();
  int cur = 0;
  for (int kt = 0; kt < LLEN / 64; kt++) {
    int kb = kt * 64;
    if (kt + 1 < LLEN / 64) {
      stage64(kg + (size_t)(kb + 64) * N3, (size_t)N3 * 2, kS[cur ^ 1], lane, wid);
      stage64(vg + kb + 64, (size_t)LLEN * 2, vS[cur ^ 1], lane, wid);
    }

    // phase pairs for this tile's owned keys: per blk, keys off..off+3
    f32x4 ph[4][2];
#pragma unroll
    for (int blk = 0; blk < 4; blk++) {
      int off = kb + ((blk & 2) << 4) + ((blk & 1) << 2) + lg * 8;
      ph[blk][0] = *reinterpret_cast<const f32x4*>(&pprow[off]);
      ph[blk][1] = *reinterpret_cast<const f32x4*>(&pprow[off + 2]);
    }

    // S^T = K Q : sv[blk][r] = S[q=qb+lc][key=f(blk, lg*4+r)]
    f32x4 sv[4];
#pragma unroll
    for (int blk = 0; blk < 4; blk++) {
      int krow = arow + ((blk & 2) << 4) + ((blk & 1) << 2);
      bf16x8 kf0 = read128s(kS[cur], krow, lg * 16);
      bf16x8 kf1 = read128s(kS[cur], krow, 64 + lg * 16);
      f32x4 z = {};
      __builtin_amdgcn_s_setprio(1);
      z = __builtin_amdgcn_mfma_f32_16x16x32_bf16(kf0, qf0, z, 0, 0, 0);
      z = __builtin_amdgcn_mfma_f32_16x16x32_bf16(kf1, qf1, z, 0, 0, 0);
      __builtin_amdgcn_s_setprio(0);
      sv[blk] = z;
    }

    // logits in log2 space: 2 fma/elem
#pragma unroll
    for (int blk = 0; blk < 4; blk++) {
#pragma unroll
      for (int r = 0; r < 4; r++) {
        f32x4 pp = ph[blk][r >> 1];
        float pk = (r & 1) ? pp.z : pp.x;
        float kbv = (r & 1) ? pp.w : pp.y;
        sv[blk][r] = fmaf(sv[blk][r], c1, fmaf(wq, pk, kbv));
      }
    }

    // tile max: in-lane over 16, then 2 shfl over lg groups
    float rm = sv[0][0];
#pragma unroll
    for (int blk = 0; blk < 4; blk++)
#pragma unroll
      for (int r = 0; r < 4; r++) rm = fmaxf(rm, sv[blk][r]);
    rm = fmaxf(rm, __shfl_xor(rm, 16, 64));
    rm = fmaxf(rm, __shfl_xor(rm, 32, 64));

    // defer-max (T13, THR=8 in log2 space -> P <= 256)
    if (!__all(rm <= mrow + 8.f)) {
      float mn = fmaxf(mrow, rm);
      float al = __builtin_amdgcn_exp2f(mrow - mn);
      mrow = mn;
      lrow *= al;
      float ao0 = __shfl(al, lg * 4 + 0, 16);
      float ao1 = __shfl(al, lg * 4 + 1, 16);
      float ao2 = __shfl(al, lg * 4 + 2, 16);
      float ao3 = __shfl(al, lg * 4 + 3, 16);
#pragma unroll
      for (int d = 0; d < 4; d++) {
        o[d][0] *= ao0; o[d][1] *= ao1; o[d][2] *= ao2; o[d][3] *= ao3;
      }
    }

    float ssum = 0.f;
#pragma unroll
    for (int blk = 0; blk < 4; blk++)
#pragma unroll
      for (int r = 0; r < 4; r++) {
        float p = __builtin_amdgcn_exp2f(sv[blk][r] - mrow);
        sv[blk][r] = p;
        ssum += p;
      }
    ssum += __shfl_xor(ssum, 16, 64);
    ssum += __shfl_xor(ssum, 32, 64);
    lrow += ssum;

    // P -> bf16 A-frags, purely in-lane
    bf16x8 pa0, pa1;
#pragma unroll
    for (int r = 0; r < 4; r++) {
      pa0[r] = (__bf16)sv[0][r];
      pa0[4 + r] = (__bf16)sv[1][r];
      pa1[r] = (__bf16)sv[2][r];
      pa1[4 + r] = (__bf16)sv[3][r];
    }

    // O += P V
#pragma unroll
    for (int d = 0; d < 4; d++) {
      bf16x8 vb0 = read128s(vS[cur], d * 16 + lc, lg * 16);
      bf16x8 vb1 = read128s(vS[cur], d * 16 + lc, 64 + lg * 16);
      __builtin_amdgcn_s_setprio(1);
      o[d] = __builtin_amdgcn_mfma_f32_16x16x32_bf16(pa0, vb0, o[d], 0, 0, 0);
      o[d] = __builtin_amdgcn_mfma_f32_16x16x32_bf16(pa1, vb1, o[d], 0, 0, 0);
      __builtin_amdgcn_s_setprio(0);
    }

    __syncthreads();  // drains staged loads; protects buffer reuse
    cur ^= 1;
  }

  // epilogue: O rows are q=qb+lg*4+r, cols dh=d*16+lc; l lives at lane lc=q
  float linv = 1.0f / lrow;
  float li0 = __shfl(linv, lg * 4 + 0, 16);
  float li1 = __shfl(linv, lg * 4 + 1, 16);
  float li2 = __shfl(linv, lg * 4 + 2, 16);
  float li3 = __shfl(linv, lg * 4 + 3, 16);
#pragma unroll
  for (int d = 0; d < 4; d++) {
    int col = h * DH + d * 16 + lc;
    size_t base = (size_t)(b * LLEN + qb + lg * 4) * DDIM + col;
    attn_out[base] = f2bf(o[d][0] * li0);
    attn_out[base + DDIM] = f2bf(o[d][1] * li1);
    attn_out[base + 2 * DDIM] = f2bf(o[d][2] * li2);
    attn_out[base + 3 * DDIM] = f2bf(o[d][3] * li3);
  }
}

extern "C" void kernel_launch(void* const* d_in, const int* in_sizes, int n_in,
                              void* d_out, int out_size, void* d_ws, size_t ws_size,
                              hipStream_t stream) {
  const float* x       = (const float*)d_in[0];
  const int*   mask    = (const int*)d_in[1];
  const float* W_qkv   = (const float*)d_in[2];
  const float* b_qkv   = (const float*)d_in[3];
  const float* W_out   = (const float*)d_in[4];
  const float* b_out   = (const float*)d_in[5];
  const float* W_phase = (const float*)d_in[6];
  const float* b_phase = (const float*)d_in[7];
  const float* rscale  = (const float*)d_in[8];
  const float* pscale  = (const float*)d_in[9];
  float* out = (float*)d_out;

  char* ws = (char*)d_ws;
  u16* x_bf     = (u16*)(ws + 0);           //  8.0 MB
  u16* wt_qkv   = (u16*)(ws + 8388608);     //  6.0 MB
  u16* wt_out   = (u16*)(ws + 14680064);    //  2.0 MB
  u16* qkv      = (u16*)(ws + 16777216);    // 24.0 MB
  u16* vT       = (u16*)(ws + 41943040);    //  8.0 MB
  u16* attn_out = (u16*)(ws + 50331648);    //  8.0 MB
  f32x2* ppk    = (f32x2*)(ws + 58720256);  //  0.5 MB

  k_cvt<<<MTOT * DDIM / 4 / 256, 256, 0, stream>>>(x, x_bf, MTOT * DDIM);
  k_transpose_w<<<dim3(DDIM / 32, N3 / 32), 256, 0, stream>>>(W_qkv, wt_qkv, DDIM, N3);
  k_transpose_w<<<dim3(DDIM / 32, DDIM / 32), 256, 0, stream>>>(W_out, wt_out, DDIM, DDIM);
  k_phase<<<MTOT, 256, 0, stream>>>(x, W_phase, b_phase, pscale, rscale, mask, ppk);
  k_gemm<true><<<dim3(MTOT / 128, N3 / 128), 256, 0, stream>>>(
      x_bf, wt_qkv, b_qkv, qkv, MTOT, N3, DDIM);
  k_vtrans<<<dim3(LLEN / 64, BB * HH), 256, 0, stream>>>(qkv, vT);
  k_attn<<<dim3(LLEN / 64, BB * HH), 256, 0, stream>>>(
      qkv, vT, ppk, rscale, attn_out);
  k_gemm<false><<<dim3(MTOT / 128, DDIM / 128), 256, 0, stream>>>(
      attn_out, wt_out, b_out, out, MTOT, DDIM, DDIM);
}

// Round 7
// 234.869 us; speedup vs baseline: 1.4159x; 1.0658x over previous
//
#include <hip/hip_runtime.h>

typedef unsigned short u16;
typedef unsigned int u32;
typedef __attribute__((ext_vector_type(2))) unsigned long long u64x2;
typedef __attribute__((ext_vector_type(4))) unsigned short u16x4;
typedef __attribute__((ext_vector_type(8))) __bf16 bf16x8;
typedef __attribute__((ext_vector_type(4))) float f32x4;
typedef __attribute__((ext_vector_type(2))) float f32x2;

#define DEV static __device__ __forceinline__
#define LOG2E 1.4426950408889634f

DEV u16 f2bf(float f) { __bf16 h = (__bf16)f; return __builtin_bit_cast(u16, h); }

// Problem constants
#define BB   2
#define LLEN 2048
#define DDIM 1024
#define HH   16
#define DH   64
#define MTOT 4096   // B*L
#define N3   3072   // 3*D

// ---------------- async global->LDS ----------------
DEV void gl16(const void* g, void* l) {
  __builtin_amdgcn_global_load_lds(
      (const __attribute__((address_space(1))) void*)g,
      (__attribute__((address_space(3))) void*)l, 16, 0, 0);
}
DEV void gl4(const void* g, void* l) {
  __builtin_amdgcn_global_load_lds(
      (const __attribute__((address_space(1))) void*)g,
      (__attribute__((address_space(3))) void*)l, 4, 0, 0);
}

// Stage a 64-row x 128B tile into linear LDS with XOR swizzle on row bits
// {0,1,3}: LDS[row*128 + cb] = G[row][cb ^ (swz3(row)<<4)],
// swz3(row) = (row&3) | (((row>>3)&1)<<2).
// (K-tile QK^T A-rows vary in row bits {0,1,3,4}; V-rows in {0..3} — both map
// to 8 distinct 16B slots per 16 lanes => 2-way = free.)
DEV void stage64(const u16* org, size_t gsb, u16* lds, int lane, int wid) {
#pragma unroll
  for (int j = 0; j < 2; j++) {
    int inst = wid * 2 + j;
    int r8 = lane >> 3;                      // row&7
    int row = inst * 8 + r8;
    int s = (r8 & 3) | ((inst & 1) << 2);    // == swz3(row)
    const char* src = (const char*)org + (size_t)row * gsb +
                      (((lane & 7) ^ s) << 4);
    gl16(src, (char*)lds + inst * 1024);
  }
}
DEV bf16x8 read128s(const u16* tile, int row, int colb) {
  return *reinterpret_cast<const bf16x8*>(
      (const char*)tile + row * 128 +
      (colb ^ (((row & 3) | (((row >> 3) & 1) << 2)) << 4)));
}

// Stage a 128-row x 64B tile: LDS[row*64 + cb] = G[row][cb ^ ((row&3)<<4)].
DEV void stage128x32(const u16* org, size_t gsb, u16* lds, int lane, int wid) {
#pragma unroll
  for (int j = 0; j < 2; j++) {
    int inst = wid + j * 4;
    int r16 = lane >> 2;
    const char* src = (const char*)org + (size_t)(inst * 16 + r16) * gsb +
                      ((((lane & 3) ^ (r16 & 3))) << 4);
    gl16(src, (char*)lds + inst * 1024);
  }
}
DEV bf16x8 read64(const u16* tile, int row, int colb) {
  return *reinterpret_cast<const bf16x8*>(
      (const char*)tile + row * 64 + (colb ^ ((row & 3) << 4)));
}

// ---------------- fp32 -> bf16 cast (x) ----------------
__global__ __launch_bounds__(256) void k_cvt(const float* __restrict__ in,
                                             u16* __restrict__ out, int n) {
  int i = (blockIdx.x * 256 + threadIdx.x) * 4;
  if (i < n) {
    f32x4 v = *reinterpret_cast<const f32x4*>(in + i);
    u16x4 o;
    o.x = f2bf(v.x); o.y = f2bf(v.y); o.z = f2bf(v.z); o.w = f2bf(v.w);
    *reinterpret_cast<u16x4*>(out + i) = o;
  }
}

// ---------------- W [K][N] fp32 -> WT [N][K] bf16 ----------------
__global__ __launch_bounds__(256) void k_transpose_w(const float* __restrict__ W,
                                                     u16* __restrict__ WT,
                                                     int K, int N) {
  __shared__ float s[32][33];
  int k0 = blockIdx.x * 32, n0 = blockIdx.y * 32;
  int tx = threadIdx.x & 31, ty = threadIdx.x >> 5;
#pragma unroll
  for (int i = 0; i < 4; i++)
    s[ty + i * 8][tx] = W[(k0 + ty + i * 8) * (size_t)N + n0 + tx];
  __syncthreads();
#pragma unroll
  for (int i = 0; i < 4; i++)
    WT[(size_t)(n0 + ty + i * 8) * K + k0 + tx] = f2bf(s[tx][ty + i * 8]);
}

// ---------------- phase: ppk[bh][l] = {pk, -rs*log2e*pk^2 (or -1e9 if masked)} ----------------
__global__ __launch_bounds__(256) void k_phase(const float* __restrict__ x,
                                               const float* __restrict__ Wp,
                                               const float* __restrict__ bp,
                                               const float* __restrict__ pscale,
                                               const float* __restrict__ rscale,
                                               const int* __restrict__ mask,
                                               f32x2* __restrict__ ppk) {
  int m = blockIdx.x;
  int t = threadIdx.x;
  int h = t & 15, j = t >> 4;
  const float* xr = x + (size_t)m * DDIM;
  float acc = 0.f;
#pragma unroll 4
  for (int kk = 0; kk < 64; kk++) {
    int k = j * 64 + kk;
    acc += xr[k] * Wp[k * HH + h];
  }
  __shared__ float s[16][17];
  s[j][h] = acc;
  __syncthreads();
  if (t < 16) {
    float sum = 0.f;
#pragma unroll
    for (int jj = 0; jj < 16; jj++) sum += s[jj][t];
    float v = tanhf((*pscale) * (sum + bp[t]));
    int b = m >> 11, l = m & (LLEN - 1);
    float kb = (mask[m] == 0) ? -1.0e9f : (-(*rscale) * LOG2E) * v * v;
    f32x2 o; o.x = v; o.y = kb;
    ppk[((size_t)(b * HH + t)) * LLEN + l] = o;
  }
}

// ---------------- 128x128 bf16 MFMA GEMM (dbuf + global_load_lds) ----------------
template <bool BF16_OUT>
__global__ __launch_bounds__(256) void k_gemm(const u16* __restrict__ A,
                                              const u16* __restrict__ BT,
                                              const float* __restrict__ bias,
                                              void* __restrict__ C,
                                              int M, int N, int K) {
  __shared__ __attribute__((aligned(16))) u16 sA[2][128 * 32];
  __shared__ __attribute__((aligned(16))) u16 sB[2][128 * 32];
  int m0 = blockIdx.x * 128, n0 = blockIdx.y * 128;
  int t = threadIdx.x, lane = t & 63, wid = t >> 6;
  int wm = wid >> 1, wn = wid & 1;
  int lc = lane & 15, lg = lane >> 4;

  const u16* Ao = A + (size_t)m0 * K;
  const u16* Bo = BT + (size_t)n0 * K;

  f32x4 acc[4][4] = {};
  stage128x32(Ao, (size_t)K * 2, sA[0], lane, wid);
  stage128x32(Bo, (size_t)K * 2, sB[0], lane, wid);
  __syncthreads();
  int cur = 0;
  int NT = K >> 5;
  for (int kt = 0; kt < NT; kt++) {
    if (kt + 1 < NT) {
      stage128x32(Ao + (kt + 1) * 32, (size_t)K * 2, sA[cur ^ 1], lane, wid);
      stage128x32(Bo + (kt + 1) * 32, (size_t)K * 2, sB[cur ^ 1], lane, wid);
    }
    bf16x8 af[4], bfr[4];
#pragma unroll
    for (int i = 0; i < 4; i++) af[i] = read64(sA[cur], wm * 64 + i * 16 + lc, lg * 16);
#pragma unroll
    for (int j = 0; j < 4; j++) bfr[j] = read64(sB[cur], wn * 64 + j * 16 + lc, lg * 16);
    __builtin_amdgcn_s_setprio(1);
#pragma unroll
    for (int i = 0; i < 4; i++)
#pragma unroll
      for (int j = 0; j < 4; j++)
        acc[i][j] = __builtin_amdgcn_mfma_f32_16x16x32_bf16(af[i], bfr[j], acc[i][j], 0, 0, 0);
    __builtin_amdgcn_s_setprio(0);
    __syncthreads();
    cur ^= 1;
  }

  int rg = lane >> 4;
#pragma unroll
  for (int i = 0; i < 4; i++) {
#pragma unroll
    for (int j = 0; j < 4; j++) {
      int col = n0 + wn * 64 + j * 16 + lc;
      float bv = bias[col];
#pragma unroll
      for (int r = 0; r < 4; r++) {
        int row = m0 + wm * 64 + i * 16 + rg * 4 + r;
        float v = acc[i][j][r] + bv;
        if (BF16_OUT)
          ((u16*)C)[(size_t)row * N + col] = f2bf(v);
        else
          ((float*)C)[(size_t)row * N + col] = v;
      }
    }
  }
}

// ---------------- V transpose: qkv v-part -> vT[b][h][dh][l] ----------------
__global__ __launch_bounds__(256) void k_vtrans(const u16* __restrict__ qkv,
                                                u16* __restrict__ vT) {
  int bh = blockIdx.y;
  int lt = blockIdx.x;
  int b = bh >> 4, h = bh & 15;
  __shared__ __attribute__((aligned(16))) u16 s[64][72];
  int t = threadIdx.x;
#pragma unroll
  for (int i = 0; i < 2; i++) {
    int c = t + i * 256;
    int l = c >> 3, ko = (c & 7) * 8;
    *reinterpret_cast<u64x2*>(&s[l][ko]) = *reinterpret_cast<const u64x2*>(
        &qkv[(size_t)(b * LLEN + lt * 64 + l) * N3 + 2 * DDIM + h * DH + ko]);
  }
  __syncthreads();
#pragma unroll
  for (int i = 0; i < 2; i++) {
    int c = t + i * 256;
    int dh = c >> 3, lo = (c & 7) * 8;
    u16 tmp[8];
#pragma unroll
    for (int j = 0; j < 8; j++) tmp[j] = s[lo + j][dh];
    *reinterpret_cast<u64x2*>(&vT[((size_t)bh * DH + dh) * LLEN + lt * 64 + lo]) =
        *reinterpret_cast<u64x2*>(tmp);
  }
}

// ---------------- flash attention, swapped QK^T, counted-vmcnt pipeline ----------------
// Key permutation: QK^T mfma #blk uses K rows f(blk,m)=32*(blk>>1)+8*(m>>2)+
// 4*(blk&1)+(m&3). Lane (lc,lg) owns S[q=qb+lc][key=f(blk,lg*4+r)] in
// sv[blk][r], which is exactly PV A-frag element order — P->PV is in-lane
// bf16 casts only. Softmax: per-lane q, in-lane reduce + 2 shfl_xor.
// Pipeline: each wave issues exactly 6 VMEM ops per tile (2 gl16 K, 2 gl16 V,
// 2 gl4 phase-pairs). s_waitcnt vmcnt(6) waits only for tile t's loads
// (in-order retirement), leaving tile t+1's 6 in flight across compute.
__global__ __launch_bounds__(256, 4) void k_attn(const u16* __restrict__ qkv,
                                                 const u16* __restrict__ vT,
                                                 const f32x2* __restrict__ ppk,
                                                 const float* __restrict__ rscale_p,
                                                 u16* __restrict__ attn_out) {
  __shared__ __attribute__((aligned(16))) u16 kS[2][64 * 64];
  __shared__ __attribute__((aligned(16))) u16 vS[2][64 * 64];
  __shared__ __attribute__((aligned(16))) float ppS[2][128];

  int bh = blockIdx.y, b = bh >> 4, h = bh & 15;
  int q0 = blockIdx.x * 64;
  int t = threadIdx.x, lane = t & 63, wid = t >> 6;
  int qb = q0 + wid * 16;
  int lc = lane & 15, lg = lane >> 4;

  const float rs2 = (*rscale_p) * LOG2E;
  const float c1 = 0.125f * LOG2E;
  const f32x2* pprow = ppk + (size_t)bh * LLEN;
  const float* pprowf = (const float*)pprow;

  // Q B-fragment: lane holds Q[qb+lc][dh=lg*8+j]
  bf16x8 qf0, qf1;
  {
    const u16* qp = &qkv[(size_t)(b * LLEN + qb + lc) * N3 + h * DH + lg * 8];
    qf0 = *reinterpret_cast<const bf16x8*>(qp);
    qf1 = *reinterpret_cast<const bf16x8*>(qp + 32);
  }
  float wq = 2.f * rs2 * pprow[qb + lc].x;   // per-lane scalar (q = lc)

  const u16* kg = qkv + (size_t)(b * LLEN) * N3 + DDIM + h * DH;  // rows: key
  const u16* vg = vT + (size_t)bh * DH * LLEN;                    // rows: dh

  // prologue: stage tile 0 (6 VMEM ops per wave)
  stage64(kg, (size_t)N3 * 2, kS[0], lane, wid);
  stage64(vg, (size_t)LLEN * 2, vS[0], lane, wid);
  gl4(pprowf + lane, &ppS[0][0]);
  gl4(pprowf + 64 + lane, &ppS[0][64]);

  f32x4 o[4] = {};
  float mrow = -1e30f, lrow = 0.f;
  int arow = ((lc >> 2) << 3) | (lc & 3);    // f(blk,lc) base

  int cur = 0;
  const int NT = LLEN / 64;
  for (int kt = 0; kt < NT; kt++) {
    int kb = kt * 64;
    if (kt + 1 < NT) {
      // stage tile t+1 into buf[cur^1] (all waves finished reading it at the
      // end-of-compute barrier of iter t-1)
      stage64(kg + (size_t)(kb + 64) * N3, (size_t)N3 * 2, kS[cur ^ 1], lane, wid);
      stage64(vg + kb + 64, (size_t)LLEN * 2, vS[cur ^ 1], lane, wid);
      const float* pt = pprowf + (size_t)(kb + 64) * 2;
      gl4(pt + lane, &ppS[cur ^ 1][0]);
      gl4(pt + 64 + lane, &ppS[cur ^ 1][64]);
      // wait tile t's 6 loads only; keep t+1's 6 in flight
      asm volatile("s_waitcnt vmcnt(6)" ::: "memory");
    } else {
      asm volatile("s_waitcnt vmcnt(0)" ::: "memory");
    }
    __builtin_amdgcn_s_barrier();

    // S^T = K Q : sv[blk][r] = S[q=qb+lc][key=f(blk, lg*4+r)]
    f32x4 sv[4];
#pragma unroll
    for (int blk = 0; blk < 4; blk++) {
      int krow = arow + ((blk & 2) << 4) + ((blk & 1) << 2);
      bf16x8 kf0 = read128s(kS[cur], krow, lg * 16);
      bf16x8 kf1 = read128s(kS[cur], krow, 64 + lg * 16);
      f32x4 z = {};
      __builtin_amdgcn_s_setprio(1);
      z = __builtin_amdgcn_mfma_f32_16x16x32_bf16(kf0, qf0, z, 0, 0, 0);
      z = __builtin_amdgcn_mfma_f32_16x16x32_bf16(kf1, qf1, z, 0, 0, 0);
      __builtin_amdgcn_s_setprio(0);
      sv[blk] = z;
    }

    // logits in log2 space; phase pairs from LDS (broadcast reads, conflict-free)
    {
      const float* pt = &ppS[cur][0];
#pragma unroll
      for (int blk = 0; blk < 4; blk++) {
        int off2 = (((blk & 2) << 4) + ((blk & 1) << 2) + lg * 8) * 2;
        f32x4 p0 = *reinterpret_cast<const f32x4*>(pt + off2);
        f32x4 p1 = *reinterpret_cast<const f32x4*>(pt + off2 + 4);
        sv[blk][0] = fmaf(sv[blk][0], c1, fmaf(wq, p0.x, p0.y));
        sv[blk][1] = fmaf(sv[blk][1], c1, fmaf(wq, p0.z, p0.w));
        sv[blk][2] = fmaf(sv[blk][2], c1, fmaf(wq, p1.x, p1.y));
        sv[blk][3] = fmaf(sv[blk][3], c1, fmaf(wq, p1.z, p1.w));
      }
    }

    // tile max: in-lane over 16, then 2 shfl over lg groups
    float rm = sv[0][0];
#pragma unroll
    for (int blk = 0; blk < 4; blk++)
#pragma unroll
      for (int r = 0; r < 4; r++) rm = fmaxf(rm, sv[blk][r]);
    rm = fmaxf(rm, __shfl_xor(rm, 16, 64));
    rm = fmaxf(rm, __shfl_xor(rm, 32, 64));

    // defer-max (T13, THR=8 in log2 space -> P <= 256)
    if (!__all(rm <= mrow + 8.f)) {
      float mn = fmaxf(mrow, rm);
      float al = __builtin_amdgcn_exp2f(mrow - mn);
      mrow = mn;
      lrow *= al;
      float ao0 = __shfl(al, lg * 4 + 0, 16);
      float ao1 = __shfl(al, lg * 4 + 1, 16);
      float ao2 = __shfl(al, lg * 4 + 2, 16);
      float ao3 = __shfl(al, lg * 4 + 3, 16);
#pragma unroll
      for (int d = 0; d < 4; d++) {
        o[d][0] *= ao0; o[d][1] *= ao1; o[d][2] *= ao2; o[d][3] *= ao3;
      }
    }

    float ssum = 0.f;
#pragma unroll
    for (int blk = 0; blk < 4; blk++)
#pragma unroll
      for (int r = 0; r < 4; r++) {
        float p = __builtin_amdgcn_exp2f(sv[blk][r] - mrow);
        sv[blk][r] = p;
        ssum += p;
      }
    ssum += __shfl_xor(ssum, 16, 64);
    ssum += __shfl_xor(ssum, 32, 64);
    lrow += ssum;

    // P -> bf16 A-frags, purely in-lane
    bf16x8 pa0, pa1;
#pragma unroll
    for (int r = 0; r < 4; r++) {
      pa0[r] = (__bf16)sv[0][r];
      pa0[4 + r] = (__bf16)sv[1][r];
      pa1[r] = (__bf16)sv[2][r];
      pa1[4 + r] = (__bf16)sv[3][r];
    }

    // O += P V
#pragma unroll
    for (int d = 0; d < 4; d++) {
      bf16x8 vb0 = read128s(vS[cur], d * 16 + lc, lg * 16);
      bf16x8 vb1 = read128s(vS[cur], d * 16 + lc, 64 + lg * 16);
      __builtin_amdgcn_s_setprio(1);
      o[d] = __builtin_amdgcn_mfma_f32_16x16x32_bf16(pa0, vb0, o[d], 0, 0, 0);
      o[d] = __builtin_amdgcn_mfma_f32_16x16x32_bf16(pa1, vb1, o[d], 0, 0, 0);
      __builtin_amdgcn_s_setprio(0);
    }

    __builtin_amdgcn_s_barrier();  // all waves done reading buf[cur]
    cur ^= 1;
  }

  // epilogue: O rows are q=qb+lg*4+r, cols dh=d*16+lc; l lives at lane lc=q
  float linv = 1.0f / lrow;
  float li0 = __shfl(linv, lg * 4 + 0, 16);
  float li1 = __shfl(linv, lg * 4 + 1, 16);
  float li2 = __shfl(linv, lg * 4 + 2, 16);
  float li3 = __shfl(linv, lg * 4 + 3, 16);
#pragma unroll
  for (int d = 0; d < 4; d++) {
    int col = h * DH + d * 16 + lc;
    size_t base = (size_t)(b * LLEN + qb + lg * 4) * DDIM + col;
    attn_out[base] = f2bf(o[d][0] * li0);
    attn_out[base + DDIM] = f2bf(o[d][1] * li1);
    attn_out[base + 2 * DDIM] = f2bf(o[d][2] * li2);
    attn_out[base + 3 * DDIM] = f2bf(o[d][3] * li3);
  }
}

extern "C" void kernel_launch(void* const* d_in, const int* in_sizes, int n_in,
                              void* d_out, int out_size, void* d_ws, size_t ws_size,
                              hipStream_t stream) {
  const float* x       = (const float*)d_in[0];
  const int*   mask    = (const int*)d_in[1];
  const float* W_qkv   = (const float*)d_in[2];
  const float* b_qkv   = (const float*)d_in[3];
  const float* W_out   = (const float*)d_in[4];
  const float* b_out   = (const float*)d_in[5];
  const float* W_phase = (const float*)d_in[6];
  const float* b_phase = (const float*)d_in[7];
  const float* rscale  = (const float*)d_in[8];
  const float* pscale  = (const float*)d_in[9];
  float* out = (float*)d_out;

  char* ws = (char*)d_ws;
  u16* x_bf     = (u16*)(ws + 0);           //  8.0 MB
  u16* wt_qkv   = (u16*)(ws + 8388608);     //  6.0 MB
  u16* wt_out   = (u16*)(ws + 14680064);    //  2.0 MB
  u16* qkv      = (u16*)(ws + 16777216);    // 24.0 MB
  u16* vT       = (u16*)(ws + 41943040);    //  8.0 MB
  u16* attn_out = (u16*)(ws + 50331648);    //  8.0 MB
  f32x2* ppk    = (f32x2*)(ws + 58720256);  //  0.5 MB

  k_cvt<<<MTOT * DDIM / 4 / 256, 256, 0, stream>>>(x, x_bf, MTOT * DDIM);
  k_transpose_w<<<dim3(DDIM / 32, N3 / 32), 256, 0, stream>>>(W_qkv, wt_qkv, DDIM, N3);
  k_transpose_w<<<dim3(DDIM / 32, DDIM / 32), 256, 0, stream>>>(W_out, wt_out, DDIM, DDIM);
  k_phase<<<MTOT, 256, 0, stream>>>(x, W_phase, b_phase, pscale, rscale, mask, ppk);
  k_gemm<true><<<dim3(MTOT / 128, N3 / 128), 256, 0, stream>>>(
      x_bf, wt_qkv, b_qkv, qkv, MTOT, N3, DDIM);
  k_vtrans<<<dim3(LLEN / 64, BB * HH), 256, 0, stream>>>(qkv, vT);
  k_attn<<<dim3(LLEN / 64, BB * HH), 256, 0, stream>>>(
      qkv, vT, ppk, rscale, attn_out);
  k_gemm<false><<<dim3(MTOT / 128, DDIM / 128), 256, 0, stream>>>(
      attn_out, wt_out, b_out, out, MTOT, DDIM, DDIM);
}